// Round 1
// baseline (102.077 us; speedup 1.0000x reference)
//
#include <hip/hip_runtime.h>
#include <math.h>

// ---------------------------------------------------------------------------
// QuantumClassifier_v2: photonic boson-sampling MLP on MI355X.
// Pipeline (all fp32 / complex64-as-float2):
//   h = (x @ W_down + b_down)/pi                      [128,10]
//   WL1,WR1,WLF,WRF = Clements interferometers        [10,10] cplx each
//   U1 = WR1 @ diag(e^{ih}) @ WL1                     [128,10,10]
//   e1 = |perm(U1[rows_nb, in_modes])|^2              [128,252]
//   phi2[m] = sum_k e1[.,k] for k%10==m               [128,10]
//   UF = WRF @ diag(e^{i phi2}) @ WLF                 [128,10,10]
//   probs = |perm(UF[rows_b, in_modes])|^2 / norm     [128,2002]
//   out = probs @ W_out + b_out                       [128,10]
// ---------------------------------------------------------------------------

#define PI_F 3.14159265358979323846f

// C(n,k) for n<=13, k<=4 (used by lexicographic combination unranking)
__constant__ int BINOM[14][5] = {
  {1, 0, 0, 0, 0},  {1, 1, 0, 0, 0},  {1, 2, 1, 0, 0},   {1, 3, 3, 1, 0},
  {1, 4, 6, 4, 1},  {1, 5,10,10, 5},  {1, 6,15,20,15},   {1, 7,21,35,35},
  {1, 8,28,56,70},  {1, 9,36,84,126}, {1,10,45,120,210}, {1,11,55,165,330},
  {1,12,66,220,495},{1,13,78,286,715}
};
__constant__ float FACTF[6] = {1.f, 1.f, 2.f, 6.f, 24.f, 120.f};

__device__ __forceinline__ float2 cmul(float2 a, float2 b) {
  return make_float2(fmaf(a.x, b.x, -a.y * b.y), fmaf(a.x, b.y, a.y * b.x));
}
__device__ __forceinline__ float2 cadd(float2 a, float2 b) {
  return make_float2(a.x + b.x, a.y + b.y);
}
__device__ __forceinline__ float2 cscale(float2 a, float s) {
  return make_float2(a.x * s, a.y * s);
}
__device__ __forceinline__ float2 imul(float2 a) {  // i*a
  return make_float2(-a.y, a.x);
}

// Lexicographic unranking of 5-combinations (strictly increasing) of {0..N-1}.
template <int N>
__device__ __forceinline__ void unrank5(int r, int c[5]) {
  int x = 0;
#pragma unroll
  for (int i = 0; i < 5; i++) {
    for (;;) {
      int cnt = BINOM[N - 1 - x][4 - i];
      if (r < cnt) { c[i] = x; x++; break; }
      r -= cnt; x++;
    }
  }
}

// Glynn permanent of a 5x5 complex matrix, Gray-code order, fully unrolled
// (delta_0 fixed +1; 16 sign patterns; result = sum/16).
__device__ __forceinline__ float2 perm5(const float2 M[5][5]) {
  float2 rs[5];
#pragma unroll
  for (int j = 0; j < 5; j++) {
    rs[j] = M[0][j];
#pragma unroll
    for (int i = 1; i < 5; i++) rs[j] = cadd(rs[j], M[i][j]);
  }
  float2 acc = cmul(cmul(cmul(cmul(rs[0], rs[1]), rs[2]), rs[3]), rs[4]);
#pragma unroll
  for (int t = 1; t < 16; t++) {
    const int g = t ^ (t >> 1);
    const int bit = (t & 1) ? 0 : ((t & 2) ? 1 : ((t & 4) ? 2 : 3));  // ctz(t)
    const int i = bit + 1;                       // row whose delta flipped
    const float step = ((g >> bit) & 1) ? -2.0f : 2.0f;
#pragma unroll
    for (int j = 0; j < 5; j++) {
      rs[j].x = fmaf(step, M[i][j].x, rs[j].x);
      rs[j].y = fmaf(step, M[i][j].y, rs[j].y);
    }
    float2 p = cmul(cmul(cmul(cmul(rs[0], rs[1]), rs[2]), rs[3]), rs[4]);
    const float s = (__popc(g) & 1) ? -1.0f : 1.0f;
    acc.x = fmaf(s, p.x, acc.x);
    acc.y = fmaf(s, p.y, acc.y);
  }
  return make_float2(acc.x * (1.0f / 16.0f), acc.y * (1.0f / 16.0f));
}

// ---------------------------------------------------------------------------
// Kernel A: blocks 0..127 -> h[b] = (x[b] @ W_down + b_down)/pi
//           blocks 128..131 -> one Clements interferometer each into Umats
// ---------------------------------------------------------------------------
__global__ __launch_bounds__(256) void k_head(
    const float* __restrict__ x, const float* __restrict__ Wd,
    const float* __restrict__ bd, const float* __restrict__ ph_l1,
    const float* __restrict__ ph_r1, const float* __restrict__ ph_lf,
    const float* __restrict__ ph_rf, float* __restrict__ h,
    float2* __restrict__ Umats) {
  const int tid = threadIdx.x;
  __shared__ float red[4][10];
  __shared__ float2 T[45][4];
  __shared__ float2 U[100];

  if (blockIdx.x < 128) {
    const int b = blockIdx.x;
    float acc[10];
#pragma unroll
    for (int c = 0; c < 10; c++) acc[c] = 0.f;
    for (int i = tid; i < 784; i += 256) {
      float xv = x[b * 784 + i];
      const float* w = Wd + i * 10;
#pragma unroll
      for (int c = 0; c < 10; c++) acc[c] = fmaf(xv, w[c], acc[c]);
    }
    const int lane = tid & 63, wave = tid >> 6;
#pragma unroll
    for (int c = 0; c < 10; c++) {
      float r = acc[c];
#pragma unroll
      for (int d = 32; d > 0; d >>= 1) r += __shfl_down(r, d);
      if (lane == 0) red[wave][c] = r;
    }
    __syncthreads();
    if (tid < 10) {
      float s = red[0][tid] + red[1][tid] + red[2][tid] + red[3][tid] + bd[tid];
      h[b * 10 + tid] = s * (1.0f / PI_F);
    }
  } else {
    const int which = blockIdx.x - 128;
    const float* ph = (which == 0) ? ph_l1
                    : (which == 1) ? ph_r1
                    : (which == 2) ? ph_lf : ph_rf;
    if (tid < 45) {
      float t1 = ph[tid * 2 + 0], t2 = ph[tid * 2 + 1];
      float s1, c1, s2, c2;
      sincosf(t1, &s1, &c1);
      sincosf(t2, &s2, &c2);
      float2 e2 = make_float2(c2, s2);
      float2 e1m = make_float2(c1 - 1.f, s1);   // e^{it1} - 1
      float2 e1p = make_float2(c1 + 1.f, s1);   // e^{it1} + 1
      T[tid][0] = cscale(cmul(e2, e1m), 0.5f);        // e2*(e1-1)/2
      T[tid][1] = cscale(cmul(e2, imul(e1p)), 0.5f);  // i*e2*(e1+1)/2
      T[tid][2] = cscale(imul(e1p), 0.5f);            // i*(e1+1)/2
      T[tid][3] = make_float2(0.5f * (1.f - c1), -0.5f * s1);  // (1-e1)/2
    }
    if (tid < 100) U[tid] = make_float2((tid % 11 == 0) ? 1.f : 0.f, 0.f);
    __syncthreads();
    int kb = 0;
    for (int layer = 0; layer < 10; layer++) {
      const int start = layer & 1;
      const int npairs = 5 - start;  // even layer: 5 MZIs, odd: 4
      if (tid < npairs * 10) {
        const int pi = tid / 10, n = tid % 10;
        const int p = start + 2 * pi;
        const int k = kb + pi;
        float2 u0 = U[p * 10 + n], u1 = U[(p + 1) * 10 + n];
        float2 n0 = cadd(cmul(T[k][0], u0), cmul(T[k][1], u1));
        float2 n1 = cadd(cmul(T[k][2], u0), cmul(T[k][3], u1));
        U[p * 10 + n] = n0;
        U[(p + 1) * 10 + n] = n1;
      }
      kb += npairs;
      __syncthreads();
    }
    if (tid < 100) Umats[which * 100 + tid] = U[tid];
  }
}

// U_out[m,n] = sum_k WR[m,k] * v[k] * WL[k,n]  (v in LDS, 100 active threads)
__device__ __forceinline__ void buildU(const float2* __restrict__ WRg,
                                       const float2* __restrict__ WLg,
                                       const float2* v, float2* __restrict__ outU,
                                       int tid, float2* A, float2* WLs) {
  if (tid < 100) {
    A[tid] = cmul(WRg[tid], v[tid % 10]);
    WLs[tid] = WLg[tid];
  }
  __syncthreads();
  if (tid < 100) {
    const int m = tid / 10, n = tid % 10;
    float2 acc = make_float2(0.f, 0.f);
#pragma unroll
    for (int k = 0; k < 10; k++)
      acc = cadd(acc, cmul(A[m * 10 + k], WLs[k * 10 + n]));
    outU[tid] = acc;
  }
}

// Kernel B: U1[b] = WR1 @ diag(e^{i h[b]}) @ WL1
__global__ __launch_bounds__(128) void k_u1(const float* __restrict__ h,
                                            const float2* __restrict__ Umats,
                                            float2* __restrict__ U1) {
  const int b = blockIdx.x, tid = threadIdx.x;
  __shared__ float2 v[10];
  __shared__ float2 A[100];
  __shared__ float2 WLs[100];
  if (tid < 10) {
    float s, c;
    sincosf(h[b * 10 + tid], &s, &c);
    v[tid] = make_float2(c, s);
  }
  __syncthreads();
  buildU(Umats + 100 /*WR1*/, Umats + 0 /*WL1*/, v, U1 + b * 100, tid, A, WLs);
}

// Kernel C: e1[b,k] = |perm(U1[b][rows_nb[k], {0,2,4,6,8}])|^2   (252 rows)
__global__ __launch_bounds__(256) void k_e1(const float2* __restrict__ U1,
                                            float* __restrict__ e1) {
  const int b = blockIdx.x, tid = threadIdx.x;
  __shared__ float2 U[100];
  if (tid < 100) U[tid] = U1[b * 100 + tid];
  __syncthreads();
  if (tid < 252) {
    int c[5];
    unrank5<10>(tid, c);
    float2 M[5][5];
#pragma unroll
    for (int i = 0; i < 5; i++)
#pragma unroll
      for (int j = 0; j < 5; j++) M[i][j] = U[c[i] * 10 + 2 * j];
    float2 p = perm5(M);
    e1[b * 252 + tid] = p.x * p.x + p.y * p.y;  // norm_nb == 1
  }
}

// Kernel D: phi2 fold + UF[b] = WRF @ diag(e^{i phi2}) @ WLF
__global__ __launch_bounds__(128) void k_uf(const float* __restrict__ e1,
                                            const float2* __restrict__ Umats,
                                            float2* __restrict__ UF) {
  const int b = blockIdx.x, tid = threadIdx.x;
  __shared__ float2 v[10];
  __shared__ float2 A[100];
  __shared__ float2 WLs[100];
  if (tid < 10) {
    float s = 0.f;
    for (int idx = tid; idx < 252; idx += 10) s += e1[b * 252 + idx];
    float sn, cs;
    sincosf(s, &sn, &cs);
    v[tid] = make_float2(cs, sn);
  }
  __syncthreads();
  buildU(Umats + 300 /*WRF*/, Umats + 200 /*WLF*/, v, UF + b * 100, tid, A, WLs);
}

// Kernel E: probs[b,k] = |perm(UF[b][rows_b[k], {0,2,4,6,8}])|^2 / norm[k]
// grid (8, 128): 8 chunks x 256 threads cover 2002 bunched states.
__global__ __launch_bounds__(256) void k_probs(const float2* __restrict__ UF,
                                               float* __restrict__ probs) {
  const int b = blockIdx.y, tid = threadIdx.x;
  const int k = blockIdx.x * 256 + tid;
  __shared__ float2 U[100];
  if (tid < 100) U[tid] = UF[b * 100 + tid];
  __syncthreads();
  if (k < 2002) {
    int c[5];
    unrank5<14>(k, c);  // strictly-increasing over 0..13
    int modes[5];
#pragma unroll
    for (int i = 0; i < 5; i++) modes[i] = c[i] - i;  // non-decreasing modes
    float2 M[5][5];
#pragma unroll
    for (int i = 0; i < 5; i++)
#pragma unroll
      for (int j = 0; j < 5; j++) M[i][j] = U[modes[i] * 10 + 2 * j];
    float2 p = perm5(M);
    float norm = 1.f;
    int run = 1;
#pragma unroll
    for (int i = 1; i < 5; i++) {
      if (modes[i] == modes[i - 1]) run++;
      else { norm *= FACTF[run]; run = 1; }
    }
    norm *= FACTF[run];
    probs[b * 2002 + k] = (p.x * p.x + p.y * p.y) / norm;
  }
}

// Kernel F: out[b] = probs[b] @ W_out + b_out
__global__ __launch_bounds__(256) void k_out(const float* __restrict__ probs,
                                             const float* __restrict__ Wout,
                                             const float* __restrict__ bout,
                                             float* __restrict__ out) {
  const int b = blockIdx.x, tid = threadIdx.x;
  __shared__ float red[4][10];
  float acc[10];
#pragma unroll
  for (int c = 0; c < 10; c++) acc[c] = 0.f;
  for (int k = tid; k < 2002; k += 256) {
    float p = probs[b * 2002 + k];
    const float* w = Wout + k * 10;
#pragma unroll
    for (int c = 0; c < 10; c++) acc[c] = fmaf(p, w[c], acc[c]);
  }
  const int lane = tid & 63, wave = tid >> 6;
#pragma unroll
  for (int c = 0; c < 10; c++) {
    float r = acc[c];
#pragma unroll
    for (int d = 32; d > 0; d >>= 1) r += __shfl_down(r, d);
    if (lane == 0) red[wave][c] = r;
  }
  __syncthreads();
  if (tid < 10) {
    float s = red[0][tid] + red[1][tid] + red[2][tid] + red[3][tid];
    out[b * 10 + tid] = s + bout[tid];
  }
}

extern "C" void kernel_launch(void* const* d_in, const int* in_sizes, int n_in,
                              void* d_out, int out_size, void* d_ws,
                              size_t ws_size, hipStream_t stream) {
  const float* x    = (const float*)d_in[0];  // [128,784]
  const float* Wd   = (const float*)d_in[1];  // [784,10]
  const float* bd   = (const float*)d_in[2];  // [10]
  const float* pl1  = (const float*)d_in[3];  // [45,2]
  const float* pr1  = (const float*)d_in[4];  // [45,2]
  const float* plf  = (const float*)d_in[5];  // [45,2]
  const float* prf  = (const float*)d_in[6];  // [45,2]
  const float* Wout = (const float*)d_in[7];  // [2002,10]
  const float* bout = (const float*)d_in[8];  // [10]
  float* out = (float*)d_out;                 // [128,10]

  // workspace layout (floats); float2 regions 8B-aligned (even offsets)
  float* ws = (float*)d_ws;
  float*  h     = ws;                        // 1280
  float2* Umats = (float2*)(ws + 1280);      // 4*100 c64 = 800 floats
  float2* U1    = (float2*)(ws + 2080);      // 128*100 c64 = 25600 floats
  float*  e1    = ws + 27680;                // 128*252 = 32256 floats
  float2* UF    = (float2*)(ws + 59936);     // 25600 floats
  float*  probs = ws + 85536;                // 128*2002 = 256256 floats
  // total: 341792 floats = ~1.37 MB

  k_head <<<132, 256, 0, stream>>>(x, Wd, bd, pl1, pr1, plf, prf, h, Umats);
  k_u1   <<<128, 128, 0, stream>>>(h, Umats, U1);
  k_e1   <<<128, 256, 0, stream>>>(U1, e1);
  k_uf   <<<128, 128, 0, stream>>>(e1, Umats, UF);
  k_probs<<<dim3(8, 128), 256, 0, stream>>>(UF, probs);
  k_out  <<<128, 256, 0, stream>>>(probs, Wout, bout, out);
}